// Round 9
// baseline (206.542 us; speedup 1.0000x reference)
//
#include <hip/hip_runtime.h>
#include <hip/hip_bf16.h>

typedef __bf16 bf16x8 __attribute__((ext_vector_type(8)));
typedef float  f32x16 __attribute__((ext_vector_type(16)));

#define ALPHA_W 0.4f
#define NTOT 65536.0f

// output layout (float elements): [out 4*256*128*128][cov 8*32*32][eigen 32*32*32]
#define OUT_MAIN 16777216
#define OUT_COV  (OUT_MAIN)
#define OUT_EIG  (OUT_MAIN + 8192)

// ws float offsets (512 gram slices config)
#define WS_PSXY  0        // 512*1024
#define WS_PSX   524288   // 512*32
#define WS_XA    540672   // 32*256
#define WS_XB    548864   // 32*256
#define WS_MUA   557056   // 4*256
#define WS_MUB   558080   // 4*256
#define WS_SMU   559104   // 4*256
#define WS_CT    560128   // 32*1024
#define WS_M     592896   // 32*1024
#define WS_T     625664   // 32*32

struct WP {
    const float* cw0; const float* cb0;
    const float* cw1; const float* cb1;
    const float* cw2; const float* cb2;
    const float* cw3; const float* cb3;
    const float* cw4; const float* cb4;
    const float* mw0; const float* mb0;
    const float* mw1; const float* mb1;
    const float* mw2; const float* mb2;
};

struct SJ { const float* X; const float* W; const float* B; float* Y; int ld; int act; };

__device__ __forceinline__ float lrelu(float x) { return x >= 0.f ? x : 0.01f * x; }

// One linear-layer slice: ROWS x (NCB cols) of Y = X @ W^T + b, K split KS ways.
template<int ROWS, int IN, int KS, int NCB, int ACT>
__device__ __forceinline__ void lin_block(const float* __restrict__ X,
                                          const float* __restrict__ Wg,
                                          const float* __restrict__ Bs,
                                          float* __restrict__ Y, int ld,
                                          int bidl, int tid) {
    constexpr int SL = IN / KS;
    constexpr int SF4 = SL / 4;
    int s = tid % KS;
    int r = (tid / KS) % ROWS;
    int c = tid / (KS * ROWS);
    int col = bidl * NCB + c;
    const float4* wp = (const float4*)(Wg + (size_t)col * IN + s * SL);
    const float4* xp = (const float4*)(X + r * IN + s * SL);
    float a0 = 0.f, a1 = 0.f, a2 = 0.f, a3 = 0.f;
    #pragma unroll
    for (int i = 0; i < SF4; ++i) {
        float4 wv = wp[i];
        float4 xv = xp[i];
        a0 = fmaf(wv.x, xv.x, a0); a1 = fmaf(wv.y, xv.y, a1);
        a2 = fmaf(wv.z, xv.z, a2); a3 = fmaf(wv.w, xv.w, a3);
    }
    float v = (a0 + a1) + (a2 + a3);
    #pragma unroll
    for (int m = 1; m < KS; m <<= 1) v += __shfl_xor(v, m, 64);
    if (s == 0) {
        float o = v + Bs[col];
        if (ACT) o = lrelu(o);
        Y[(size_t)r * ld + col] = o;
    }
}

// ---------- K1: blocks 0..31 ct-L0, 32..63 mu-M0, 64..575 gram (512 slices) ----------
__global__ __launch_bounds__(256, 2) void front(const float* __restrict__ cA,
                                                const float* __restrict__ sB,
                                                WP wp,
                                                float* __restrict__ pSXY,
                                                float* __restrict__ pSX,
                                                float* __restrict__ XA,
                                                float* __restrict__ MUA) {
    int bid = blockIdx.x;
    int tid = threadIdx.x;
    if (bid < 64) {
        if (bid < 32) {
            lin_block<32, 32, 1, 8, 1>(sB, wp.cw0, wp.cb0, XA, 256, bid, tid);
        } else {
            lin_block<4, 256, 8, 8, 1>(sB, wp.mw0, wp.mb0, MUA, 256, bid - 32, tid);
        }
        return;
    }
    // -------- gram partials (verified inner loop, r4 config) --------
    int gbid = bid - 64;
    int g = gbid >> 6, slice = gbid & 63;
    int w = tid >> 6, l = tid & 63;
    int col = l & 31, kq = l >> 5;
    int nbase = slice * 1024 + w * 256;     // stays inside one b
    int b = nbase >> 14, hw0 = nbase & 16383;
    const float* base = cA + (((size_t)(b * 256 + g * 32 + col)) << 14) + hw0 + kq * 8;
    f32x16 acc;
    #pragma unroll
    for (int r = 0; r < 16; r++) acc[r] = 0.f;
    float s0 = 0.f, s1 = 0.f;
    #pragma unroll 8
    for (int it = 0; it < 16; ++it) {
        float4 f0 = *(const float4*)(base + it * 16);
        float4 f1 = *(const float4*)(base + it * 16 + 4);
        s0 += (f0.x + f0.y) + (f0.z + f0.w);
        s1 += (f1.x + f1.y) + (f1.z + f1.w);
        bf16x8 v;
        v[0] = (__bf16)f0.x; v[1] = (__bf16)f0.y; v[2] = (__bf16)f0.z; v[3] = (__bf16)f0.w;
        v[4] = (__bf16)f1.x; v[5] = (__bf16)f1.y; v[6] = (__bf16)f1.z; v[7] = (__bf16)f1.w;
        acc = __builtin_amdgcn_mfma_f32_32x32x16_bf16(v, v, acc, 0, 0, 0);
    }
    __shared__ float red[4][1024];
    __shared__ float sxr[4][64];
    sxr[w][l] = s0 + s1;
    #pragma unroll
    for (int r = 0; r < 16; r++) {
        int i = (r & 3) + 8 * (r >> 2) + 4 * kq;   // 32x32 C/D layout
        red[w][i * 32 + col] = acc[r];
    }
    __syncthreads();
    for (int e = tid; e < 1024; e += 256)
        pSXY[(size_t)gbid * 1024 + e] = red[0][e] + red[1][e] + red[2][e] + red[3][e];
    if (tid < 32) {
        float v = 0.f;
        #pragma unroll
        for (int ww = 0; ww < 4; ww++) v += sxr[ww][tid] + sxr[ww][tid + 32];
        pSX[gbid * 32 + tid] = v;
    }
}

// ---------- K-stage: blocks [0,nbA) ct layer (32 rows, 1 col/block),
//            rest mu layer (4 rows, 8 cols/block) ----------
__global__ __launch_bounds__(256) void stage(SJ a, SJ m, int nbA) {
    int bid = blockIdx.x, tid = threadIdx.x;
    if (bid < nbA) {
        if (a.act) lin_block<32, 256, 8, 1, 1>(a.X, a.W, a.B, a.Y, a.ld, bid, tid);
        else       lin_block<32, 256, 8, 1, 0>(a.X, a.W, a.B, a.Y, a.ld, bid, tid);
    } else {
        int bl = bid - nbA;
        if (m.act) lin_block<4, 256, 8, 8, 1>(m.X, m.W, m.B, m.Y, m.ld, bl, tid);
        else       lin_block<4, 256, 8, 8, 0>(m.X, m.W, m.B, m.Y, m.ld, bl, tid);
    }
}

// ---------- K-finalize: blocks 0..31 (b,g) U/eigen/UDU -> M,T; blocks 32..39 cov ----------
__global__ __launch_bounds__(256, 2) void finalize(const float* __restrict__ CT,
                                                   const float* __restrict__ SMU,
                                                   const float* __restrict__ pSXY,
                                                   const float* __restrict__ pSX,
                                                   float* __restrict__ M,
                                                   float* __restrict__ T,
                                                   float* __restrict__ out) {
    int bid = blockIdx.x, t = threadIdx.x;
    __shared__ float sxg[32];
    if (bid < 32) {
        int b = bid >> 3, g = bid & 7;
        __shared__ float sct[32 * 33], uu[32 * 33], ud[32 * 33], dinv[32];
        for (int e = t; e < 1024; e += 256) sct[(e >> 5) * 33 + (e & 31)] = CT[bid * 1024 + e];
        if (t < 32) {
            float s = 0.f;
            #pragma unroll 8
            for (int sl = 0; sl < 64; sl++) s += pSX[(g * 64 + sl) * 32 + t];
            sxg[t] = s * (1.0f / NTOT);
        }
        __syncthreads();
        if (t < 32) {
            float s = 0.f;
            #pragma unroll
            for (int i = 0; i < 32; i++) { float v = sct[i * 33 + t]; s = fmaf(v, v, s); }
            dinv[t] = 1.0f / sqrtf(s);
        }
        __syncthreads();
        float* eig = out + OUT_EIG + (size_t)(g * 4 + b) * 1024;
        for (int e = t; e < 1024; e += 256) {
            int i = e >> 5, jj = e & 31;
            float u = sct[i * 33 + jj] * dinv[jj];
            uu[i * 33 + jj] = u;
            eig[e] = u;
        }
        __syncthreads();
        float* Mo = M + (size_t)bid * 1024;
        for (int e = t; e < 1024; e += 256) {
            int i = e >> 5, k = e & 31;
            float s = 0.f;
            #pragma unroll
            for (int jv = 0; jv < 32; jv++) s = fmaf(sct[i * 33 + jv], uu[k * 33 + jv], s);
            ud[i * 33 + k] = s;
            Mo[e] = ALPHA_W * s + (i == k ? (1.0f - ALPHA_W) : 0.0f);
        }
        __syncthreads();
        if (t < 32) {
            float s = 0.f;
            #pragma unroll
            for (int k = 0; k < 32; k++) s = fmaf(ud[t * 33 + k], sxg[k], s);
            T[bid * 32 + t] = ALPHA_W * (SMU[bid * 32 + t] - s);
        }
    } else {
        int g = bid - 32;
        if (t < 32) {
            float s = 0.f;
            #pragma unroll 8
            for (int sl = 0; sl < 64; sl++) s += pSX[(g * 64 + sl) * 32 + t];
            sxg[t] = s * (1.0f / NTOT);
        }
        __syncthreads();
        float* cov = out + OUT_COV + (size_t)g * 1024;
        for (int e = t; e < 1024; e += 256) {
            float s = 0.f;
            #pragma unroll 8
            for (int sl = 0; sl < 64; sl++) s += pSXY[(size_t)(g * 64 + sl) * 1024 + e];
            int i = e >> 5, jj = e & 31;
            float vv = (s - NTOT * sxg[i] * sxg[jj]) * (1.0f / (NTOT - 1.0f));
            if (i == jj) vv += 1e-5f;
            cov[e] = vv;
        }
    }
}

// ---------- K2: 1024 blocks; full 512-px tile staged once (64 KB LDS), single phase ----------
__global__ __launch_bounds__(256, 2) void color_k(const float* __restrict__ cA,
                                                  const float* __restrict__ M,
                                                  const float* __restrict__ T,
                                                  float* __restrict__ out) {
    __shared__ float xs[32 * 512];   // 64 KB: 32 channels x 512 px
    __shared__ float Ml[1024];
    __shared__ float tl[32];
    int bid = blockIdx.x;
    int tid = threadIdx.x;
    int bg = bid >> 5, chunk = bid & 31;
    int b = bg >> 3, g = bg & 7;

    for (int e = tid; e < 1024; e += 256) Ml[e] = M[(size_t)bg * 1024 + e];
    if (tid < 32) tl[tid] = T[bg * 32 + tid];

    size_t rowbase = ((size_t)(b * 256 + g * 32)) << 14;
    int ih = tid >> 6, n = tid & 63;           // output: 8 channels x 8 px-cols per thread
    int sch = tid >> 3, sp = (tid & 7) * 4;    // staging: channel sch, px sp + i*32

    // ---- stage 32ch x 512px; 16 independent float4 loads per thread ----
    const float* src = cA + rowbase + ((size_t)sch << 14) + chunk * 512 + sp;
    float* dstl = xs + sch * 512 + sp;
    #pragma unroll
    for (int i = 0; i < 16; ++i)
        *(float4*)(dstl + i * 32) = *(const float4*)(src + i * 32);
    __syncthreads();

    float acc[8][8];
    #pragma unroll
    for (int c = 0; c < 8; ++c) {
        float t0 = tl[ih * 8 + c];
        #pragma unroll
        for (int t = 0; t < 8; ++t) acc[c][t] = t0;
    }
    #pragma unroll 2
    for (int k = 0; k < 32; ++k) {
        float m[8];
        #pragma unroll
        for (int c = 0; c < 8; ++c) m[c] = Ml[(ih * 8 + c) * 32 + k];   // wave-uniform broadcast
        float xv[8];
        #pragma unroll
        for (int t = 0; t < 8; ++t) xv[t] = xs[k * 512 + t * 64 + n];   // 2 lanes/bank = free
        #pragma unroll
        for (int c = 0; c < 8; ++c)
            #pragma unroll
            for (int t = 0; t < 8; ++t)
                acc[c][t] = fmaf(m[c], xv[t], acc[c][t]);
    }
    #pragma unroll
    for (int c = 0; c < 8; ++c) {
        float* d = out + rowbase + (((size_t)(ih * 8 + c)) << 14) + chunk * 512 + n;
        #pragma unroll
        for (int t = 0; t < 8; ++t) d[t * 64] = acc[c][t];
    }
}

extern "C" void kernel_launch(void* const* d_in, const int* in_sizes, int n_in,
                              void* d_out, int out_size, void* d_ws, size_t ws_size,
                              hipStream_t stream) {
    (void)in_sizes; (void)n_in; (void)out_size; (void)ws_size;
    const float* cA = (const float*)d_in[0];
    const float* sB = (const float*)d_in[1];
    WP wp;
    wp.cw0 = (const float*)d_in[3];  wp.cb0 = (const float*)d_in[4];
    wp.cw1 = (const float*)d_in[5];  wp.cb1 = (const float*)d_in[6];
    wp.cw2 = (const float*)d_in[7];  wp.cb2 = (const float*)d_in[8];
    wp.cw3 = (const float*)d_in[9];  wp.cb3 = (const float*)d_in[10];
    wp.cw4 = (const float*)d_in[11]; wp.cb4 = (const float*)d_in[12];
    wp.mw0 = (const float*)d_in[13]; wp.mb0 = (const float*)d_in[14];
    wp.mw1 = (const float*)d_in[15]; wp.mb1 = (const float*)d_in[16];
    wp.mw2 = (const float*)d_in[17]; wp.mb2 = (const float*)d_in[18];
    float* W = (float*)d_ws;
    float* out = (float*)d_out;

    front<<<576, 256, 0, stream>>>(cA, sB, wp, W + WS_PSXY, W + WS_PSX,
                                   W + WS_XA, W + WS_MUA);
    SJ a, m;
    a = {W + WS_XA, wp.cw1, wp.cb1, W + WS_XB, 256, 1};
    m = {W + WS_MUA, wp.mw1, wp.mb1, W + WS_MUB, 256, 1};
    stage<<<288, 256, 0, stream>>>(a, m, 256);
    a = {W + WS_XB, wp.cw2, wp.cb2, W + WS_XA, 256, 1};
    m = {W + WS_MUB, wp.mw2, wp.mb2, W + WS_SMU, 256, 0};
    stage<<<288, 256, 0, stream>>>(a, m, 256);
    a = {W + WS_XA, wp.cw3, wp.cb3, W + WS_XB, 256, 1};
    stage<<<256, 256, 0, stream>>>(a, a, 256);
    a = {W + WS_XB, wp.cw4, wp.cb4, W + WS_CT, 1024, 0};
    stage<<<1024, 256, 0, stream>>>(a, a, 1024);

    finalize<<<40, 256, 0, stream>>>(W + WS_CT, W + WS_SMU, W + WS_PSXY, W + WS_PSX,
                                     W + WS_M, W + WS_T, out);
    color_k<<<1024, 256, 0, stream>>>(cA, W + WS_M, W + WS_T, out);
}

// Round 10
// 196.926 us; speedup vs baseline: 1.0488x; 1.0488x over previous
//
#include <hip/hip_runtime.h>
#include <hip/hip_bf16.h>

typedef __bf16 bf16x8 __attribute__((ext_vector_type(8)));
typedef float  f32x16 __attribute__((ext_vector_type(16)));

#define ALPHA_W 0.4f
#define NTOT 65536.0f

// output layout (float elements): [out 4*256*128*128][cov 8*32*32][eigen 32*32*32]
#define OUT_MAIN 16777216
#define OUT_COV  (OUT_MAIN)
#define OUT_EIG  (OUT_MAIN + 8192)

// ws float offsets
#define WS_PSXY  0        // 512*1024 gram partials
#define WS_PSX   524288   // 512*32 channel-sum partials
#define WS_XA    540672   // 32*256 ct activations ping
#define WS_XB    548864   // 32*256 ct activations pong
#define WS_MUA   557056   // 4*256
#define WS_MUB   558080   // 4*256
#define WS_SMU   559104   // 4*256
#define WS_CT    560128   // 32*1024 s_CT

struct WP {
    const float* cw0; const float* cb0;
    const float* cw1; const float* cb1;
    const float* cw2; const float* cb2;
    const float* cw3; const float* cb3;
    const float* cw4; const float* cb4;
    const float* mw0; const float* mb0;
    const float* mw1; const float* mb1;
    const float* mw2; const float* mb2;
};

struct SJ { const float* X; const float* W; const float* B; float* Y; int ld; int act; };

__device__ __forceinline__ float lrelu(float x) { return x >= 0.f ? x : 0.01f * x; }

// One linear-layer block: ROWS x cols GEMM slice, K split KS ways, NCB cols per block.
// thread = ((c * ROWS + r) * KS + s); all loads independent -> 1-2 latency rounds.
template<int ROWS, int IN, int KS, int NCB, int ACT>
__device__ __forceinline__ void lin_block(const float* __restrict__ X,
                                          const float* __restrict__ Wg,
                                          const float* __restrict__ Bs,
                                          float* __restrict__ Y, int ld,
                                          int bidl, int tid) {
    constexpr int SL = IN / KS;        // k-slice length (floats)
    constexpr int SF4 = SL / 4;
    int s = tid % KS;
    int r = (tid / KS) % ROWS;
    int c = tid / (KS * ROWS);         // 0..NCB-1
    int col = bidl * NCB + c;
    const float4* wp = (const float4*)(Wg + (size_t)col * IN + s * SL);
    const float4* xp = (const float4*)(X + r * IN + s * SL);
    float a0 = 0.f, a1 = 0.f, a2 = 0.f, a3 = 0.f;
    #pragma unroll
    for (int i = 0; i < SF4; ++i) {
        float4 wv = wp[i];
        float4 xv = xp[i];
        a0 = fmaf(wv.x, xv.x, a0); a1 = fmaf(wv.y, xv.y, a1);
        a2 = fmaf(wv.z, xv.z, a2); a3 = fmaf(wv.w, xv.w, a3);
    }
    float v = (a0 + a1) + (a2 + a3);
    #pragma unroll
    for (int m = 1; m < KS; m <<= 1) v += __shfl_xor(v, m, 64);
    if (s == 0) {
        float o = v + Bs[col];
        if (ACT) o = lrelu(o);
        Y[(size_t)r * ld + col] = o;
    }
}

// ---------- K1: blocks 0..31 ct-L0, 32..63 mu-M0, 64..575 gram ----------
__global__ __launch_bounds__(256, 2) void front(const float* __restrict__ cA,
                                                const float* __restrict__ sB,
                                                WP wp,
                                                float* __restrict__ pSXY,
                                                float* __restrict__ pSX,
                                                float* __restrict__ XA,
                                                float* __restrict__ MUA) {
    int bid = blockIdx.x;
    int tid = threadIdx.x;
    if (bid < 64) {
        if (bid < 32) {
            // ct-L0: Y[32][256], X = sB as [32][32]
            lin_block<32, 32, 1, 8, 1>(sB, wp.cw0, wp.cb0, XA, 256, bid, tid);
        } else {
            // mu-M0: Y[4][256], X = sB as [4][256]
            lin_block<4, 256, 8, 8, 1>(sB, wp.mw0, wp.mb0, MUA, 256, bid - 32, tid);
        }
        return;
    }
    // -------- gram partials (verified inner loop, unchanged) --------
    int gbid = bid - 64;
    int g = gbid >> 6, slice = gbid & 63;
    int w = tid >> 6, l = tid & 63;
    int col = l & 31, kq = l >> 5;
    int nbase = slice * 1024 + w * 256;     // stays inside one b
    int b = nbase >> 14, hw0 = nbase & 16383;
    const float* base = cA + (((size_t)(b * 256 + g * 32 + col)) << 14) + hw0 + kq * 8;
    f32x16 acc;
    #pragma unroll
    for (int r = 0; r < 16; r++) acc[r] = 0.f;
    float s0 = 0.f, s1 = 0.f;
    #pragma unroll 8
    for (int it = 0; it < 16; ++it) {
        float4 f0 = *(const float4*)(base + it * 16);
        float4 f1 = *(const float4*)(base + it * 16 + 4);
        s0 += (f0.x + f0.y) + (f0.z + f0.w);
        s1 += (f1.x + f1.y) + (f1.z + f1.w);
        bf16x8 v;
        v[0] = (__bf16)f0.x; v[1] = (__bf16)f0.y; v[2] = (__bf16)f0.z; v[3] = (__bf16)f0.w;
        v[4] = (__bf16)f1.x; v[5] = (__bf16)f1.y; v[6] = (__bf16)f1.z; v[7] = (__bf16)f1.w;
        acc = __builtin_amdgcn_mfma_f32_32x32x16_bf16(v, v, acc, 0, 0, 0);
    }
    __shared__ float red[4][1024];
    __shared__ float sxr[4][64];
    sxr[w][l] = s0 + s1;
    #pragma unroll
    for (int r = 0; r < 16; r++) {
        int i = (r & 3) + 8 * (r >> 2) + 4 * kq;   // 32x32 C/D layout
        red[w][i * 32 + col] = acc[r];
    }
    __syncthreads();
    for (int e = tid; e < 1024; e += 256)
        pSXY[(size_t)gbid * 1024 + e] = red[0][e] + red[1][e] + red[2][e] + red[3][e];
    if (tid < 32) {
        float v = 0.f;
        #pragma unroll
        for (int ww = 0; ww < 4; ww++) v += sxr[ww][tid] + sxr[ww][tid + 32];
        pSX[gbid * 32 + tid] = v;
    }
}

// ---------- K-stage: blocks [0,nbA) ct layer (32 rows), rest mu layer (4 rows) ----------
__global__ __launch_bounds__(256) void stage(SJ a, SJ m, int nbA) {
    int bid = blockIdx.x, tid = threadIdx.x;
    if (bid < nbA) {
        if (a.act) lin_block<32, 256, 4, 2, 1>(a.X, a.W, a.B, a.Y, a.ld, bid, tid);
        else       lin_block<32, 256, 4, 2, 0>(a.X, a.W, a.B, a.Y, a.ld, bid, tid);
    } else {
        int bl = bid - nbA;
        if (m.act) lin_block<4, 256, 8, 8, 1>(m.X, m.W, m.B, m.Y, m.ld, bl, tid);
        else       lin_block<4, 256, 8, 8, 0>(m.X, m.W, m.B, m.Y, m.ld, bl, tid);
    }
}

// ---------- K2: blocks 0..1023 color (+per-block M/T recompute, chunk0 writes eigen); 1024..1031 cov ----------
__global__ __launch_bounds__(256) void color_fused(const float* __restrict__ cA,
                                                   const float* __restrict__ CT,
                                                   const float* __restrict__ SMU,
                                                   const float* __restrict__ pSX,
                                                   const float* __restrict__ pSXY,
                                                   float* __restrict__ out) {
    __shared__ float sct[32 * 33];
    __shared__ float sctd[32 * 33];
    __shared__ float Ml[1024];
    __shared__ float tl[32];
    __shared__ float sxg[32];
    __shared__ float dinv[32];
    __shared__ float xs[2][2048];
    int bid = blockIdx.x;
    int tid = threadIdx.x;

    if (bid >= 1024) {
        // -------- cov output per group --------
        int g = bid - 1024;
        if (tid < 32) {
            float s = 0.f;
            #pragma unroll
            for (int sl = 0; sl < 64; sl++) s += pSX[(g * 64 + sl) * 32 + tid];
            sxg[tid] = s * (1.0f / NTOT);
        }
        __syncthreads();
        float* cov = out + OUT_COV + (size_t)g * 1024;
        for (int e = tid; e < 1024; e += 256) {
            float s = 0.f;
            #pragma unroll
            for (int sl = 0; sl < 64; sl++) s += pSXY[(size_t)(g * 64 + sl) * 1024 + e];
            int i = e >> 5, jj = e & 31;
            float vv = (s - NTOT * sxg[i] * sxg[jj]) * (1.0f / (NTOT - 1.0f));
            if (i == jj) vv += 1e-5f;
            cov[e] = vv;
        }
        return;
    }

    int bg = bid >> 5, chunk = bid & 31;
    int b = bg >> 3, g = bg & 7;

    // ---- prologue: recompute M (=alpha*UDU+0.6I) and T for this (b,g) ----
    for (int e = tid; e < 1024; e += 256) sct[(e >> 5) * 33 + (e & 31)] = CT[(size_t)bg * 1024 + e];
    if (tid < 32) {
        float s = 0.f;
        #pragma unroll
        for (int sl = 0; sl < 64; sl++) s += pSX[(g * 64 + sl) * 32 + tid];
        sxg[tid] = s * (1.0f / NTOT);
    }
    __syncthreads();
    if (tid < 32) {
        float s = 0.f;
        #pragma unroll
        for (int i = 0; i < 32; i++) { float v = sct[i * 33 + tid]; s = fmaf(v, v, s); }
        dinv[tid] = 1.0f / sqrtf(s);
    }
    __syncthreads();
    for (int e = tid; e < 1024; e += 256) {
        int i = e >> 5, j = e & 31;
        sctd[i * 33 + j] = sct[i * 33 + j] * dinv[j];   // = U[i][j]
    }
    __syncthreads();
    if (chunk == 0) {
        float* eig = out + OUT_EIG + (size_t)(g * 4 + b) * 1024;
        for (int e = tid; e < 1024; e += 256) eig[e] = sctd[(e >> 5) * 33 + (e & 31)];
    }
    for (int e = tid; e < 1024; e += 256) {
        int i = e >> 5, k = e & 31;
        float s = 0.f;
        #pragma unroll
        for (int j = 0; j < 32; j++) s = fmaf(sct[i * 33 + j], sctd[k * 33 + j], s);
        Ml[e] = ALPHA_W * s + (i == k ? (1.0f - ALPHA_W) : 0.0f);
    }
    __syncthreads();
    if (tid < 32) {
        float s = 0.f;
        #pragma unroll
        for (int k = 0; k < 32; k++) s = fmaf(Ml[tid * 32 + k], sxg[k], s);
        // alpha*sum(UDU*sxg) = s - 0.6*sxg[t]  (Ml = alpha*UDU + 0.6I)
        tl[tid] = ALPHA_W * SMU[bg * 32 + tid] - s + (1.0f - ALPHA_W) * sxg[tid];
    }
    // (tile loop's first __syncthreads orders tl before use)

    // ---- main coloring loop with explicit register prefetch ----
    int n = tid & 63, ih = tid >> 6;
    size_t cbase = (((size_t)(b * 256 + g * 32)) << 14) + chunk * 512;
    int srow = tid >> 3, scol = (tid & 7) * 8;
    size_t obase = (((size_t)(b * 256 + g * 32 + ih * 8)) << 14) + chunk * 512 + n;
    const float* src0 = cA + cbase + (size_t)srow * 16384 + scol;
    float4 u0 = *(const float4*)src0;
    float4 u1 = *(const float4*)(src0 + 4);
    for (int tile = 0; tile < 8; ++tile) {
        float* xd = &xs[tile & 1][srow * 64 + scol];
        *(float4*)xd = u0;
        *(float4*)(xd + 4) = u1;
        if (tile < 7) {
            const float* src = cA + cbase + (size_t)srow * 16384 + (tile + 1) * 64 + scol;
            u0 = *(const float4*)src;
            u1 = *(const float4*)(src + 4);
        }
        __syncthreads();
        const float* xb = xs[tile & 1];
        float acc[8];
        #pragma unroll
        for (int i = 0; i < 8; i++) acc[i] = tl[ih * 8 + i];
        #pragma unroll
        for (int k = 0; k < 32; k++) {
            float xv = xb[k * 64 + n];
            #pragma unroll
            for (int i = 0; i < 8; i++) acc[i] = fmaf(Ml[(ih * 8 + i) * 32 + k], xv, acc[i]);
        }
        float* dst = out + obase + tile * 64;
        #pragma unroll
        for (int i = 0; i < 8; i++) dst[(size_t)i << 14] = acc[i];
    }
}

extern "C" void kernel_launch(void* const* d_in, const int* in_sizes, int n_in,
                              void* d_out, int out_size, void* d_ws, size_t ws_size,
                              hipStream_t stream) {
    (void)in_sizes; (void)n_in; (void)out_size; (void)ws_size;
    const float* cA = (const float*)d_in[0];
    const float* sB = (const float*)d_in[1];
    WP wp;
    wp.cw0 = (const float*)d_in[3];  wp.cb0 = (const float*)d_in[4];
    wp.cw1 = (const float*)d_in[5];  wp.cb1 = (const float*)d_in[6];
    wp.cw2 = (const float*)d_in[7];  wp.cb2 = (const float*)d_in[8];
    wp.cw3 = (const float*)d_in[9];  wp.cb3 = (const float*)d_in[10];
    wp.cw4 = (const float*)d_in[11]; wp.cb4 = (const float*)d_in[12];
    wp.mw0 = (const float*)d_in[13]; wp.mb0 = (const float*)d_in[14];
    wp.mw1 = (const float*)d_in[15]; wp.mb1 = (const float*)d_in[16];
    wp.mw2 = (const float*)d_in[17]; wp.mb2 = (const float*)d_in[18];
    float* W = (float*)d_ws;
    float* out = (float*)d_out;

    front<<<576, 256, 0, stream>>>(cA, sB, wp, W + WS_PSXY, W + WS_PSX,
                                   W + WS_XA, W + WS_MUA);
    SJ a, m;
    a = {W + WS_XA, wp.cw1, wp.cb1, W + WS_XB, 256, 1};
    m = {W + WS_MUA, wp.mw1, wp.mb1, W + WS_MUB, 256, 1};
    stage<<<160, 256, 0, stream>>>(a, m, 128);
    a = {W + WS_XB, wp.cw2, wp.cb2, W + WS_XA, 256, 1};
    m = {W + WS_MUB, wp.mw2, wp.mb2, W + WS_SMU, 256, 0};
    stage<<<160, 256, 0, stream>>>(a, m, 128);
    a = {W + WS_XA, wp.cw3, wp.cb3, W + WS_XB, 256, 1};
    stage<<<128, 256, 0, stream>>>(a, a, 128);
    a = {W + WS_XB, wp.cw4, wp.cb4, W + WS_CT, 1024, 0};
    stage<<<512, 256, 0, stream>>>(a, a, 512);

    color_fused<<<1032, 256, 0, stream>>>(cA, W + WS_CT, W + WS_SMU,
                                          W + WS_PSX, W + WS_PSXY, out);
}